// Round 2
// 5336.784 us; speedup vs baseline: 1.5375x; 1.5375x over previous
//
#include <hip/hip_runtime.h>
#include <math.h>

namespace {

constexpr int cD = 512;
constexpr int cL = 512;
constexpr int cV = 32000;
constexpr int cNB = 2;
constexpr int cB = 4;
constexpr float cSCALE = 22.627416997969522f;  // sqrt(512)
constexpr float cISQ = 0.125f;                  // 1/sqrt(64)

typedef short bf16x8 __attribute__((ext_vector_type(8)));
typedef float f32x4 __attribute__((ext_vector_type(4)));

// round-to-nearest-even float -> bf16 (as ushort bits)
__device__ __forceinline__ unsigned short bf16rn(float x) {
  unsigned u = __float_as_uint(x);
  return (unsigned short)((u + 0x7fffu + ((u >> 16) & 1u)) >> 16);
}
__device__ __forceinline__ float b2f(short s) {
  return __uint_as_float(((unsigned)(unsigned short)s) << 16);
}
// 3-plane split: x = p0 + p1 + p2 + eps, |eps| <= 2^-27 |x|
__device__ __forceinline__ void split3w(float x, short& p0, short& p1, short& p2) {
  unsigned short h0 = bf16rn(x);
  float r1 = x - b2f((short)h0);
  unsigned short h1 = bf16rn(r1);
  float r2 = r1 - b2f((short)h1);
  p0 = (short)h0; p1 = (short)h1; p2 = (short)bf16rn(r2);
}
__device__ __forceinline__ float rec3(const short* a, const short* b, const short* c,
                                      long long off) {
  return b2f(a[off]) + b2f(b[off]) + b2f(c[off]);
}
// async global->LDS, 16B per lane (dest must be wave-base + lane*16 linear)
__device__ __forceinline__ void gload16(const void* g, void* l) {
  __builtin_amdgcn_global_load_lds(
      (const __attribute__((address_space(1))) unsigned int*)g,
      (__attribute__((address_space(3))) unsigned int*)l, 16, 0, 0);
}

// ---------------------------------------------------------------------------
// fp32 SIMT NT GEMM (setup only: cand / peproj / fusion)
// EPI: 0 plain | 1 cand | 2 fusion
// ---------------------------------------------------------------------------
struct GemmP {
  const float* A; int lda; long long sAz; int divA;
  const float* W; int ldw; long long sWz; int modW;
  float* C; int ldc; long long sCz;
  int Kd;
  const float* aux1;
  const float* aux2;
  const float* aux3;
  const float* bvec;
  const int* itok;
};

template <int EPI>
__global__ __launch_bounds__(256) void gemm_k(GemmP p) {
  const int z = blockIdx.z;
  const float* __restrict__ A = p.A + (long long)(z / p.divA) * p.sAz;
  const float* __restrict__ W = p.W + (long long)(z % p.modW) * p.sWz;
  float* __restrict__ C = p.C + (long long)z * p.sCz;
  const float* bv = nullptr;
  if (EPI == 1 || EPI == 2) bv = p.bvec + (long long)(z % p.modW) * cD;

  const int row0 = blockIdx.y * 128;
  const int col0 = blockIdx.x * 128;
  __shared__ float As[16][132];
  __shared__ float Bs[16][132];
  const int tid = threadIdx.x;
  const int tx = tid & 15;
  const int ty = tid >> 4;

  float acc[8][8];
#pragma unroll
  for (int i = 0; i < 8; ++i)
#pragma unroll
    for (int j = 0; j < 8; ++j) acc[i][j] = 0.0f;

  for (int k0 = 0; k0 < p.Kd; k0 += 16) {
#pragma unroll
    for (int i = 0; i < 2; ++i) {
      const int slot = tid + i * 256;
      const int rr = slot >> 2;
      const int kq = (slot & 3) << 2;
      float4 a4 = *(const float4*)(A + (long long)(row0 + rr) * p.lda + k0 + kq);
      As[kq + 0][rr] = a4.x; As[kq + 1][rr] = a4.y;
      As[kq + 2][rr] = a4.z; As[kq + 3][rr] = a4.w;
      float4 w4 = *(const float4*)(W + (long long)(col0 + rr) * p.ldw + k0 + kq);
      Bs[kq + 0][rr] = w4.x; Bs[kq + 1][rr] = w4.y;
      Bs[kq + 2][rr] = w4.z; Bs[kq + 3][rr] = w4.w;
    }
    __syncthreads();
#pragma unroll
    for (int kk = 0; kk < 16; ++kk) {
      float av[8], bw[8];
      *(float4*)&av[0] = *(const float4*)&As[kk][ty * 8];
      *(float4*)&av[4] = *(const float4*)&As[kk][ty * 8 + 4];
      *(float4*)&bw[0] = *(const float4*)&Bs[kk][tx * 8];
      *(float4*)&bw[4] = *(const float4*)&Bs[kk][tx * 8 + 4];
#pragma unroll
      for (int i = 0; i < 8; ++i)
#pragma unroll
        for (int j = 0; j < 8; ++j) acc[i][j] = fmaf(av[i], bw[j], acc[i][j]);
    }
    __syncthreads();
  }

#pragma unroll
  for (int i = 0; i < 8; ++i) {
    const int r = row0 + ty * 8 + i;
    long long prow = 0, tokoff = 0;
    if (EPI == 2) {
      const int bb = r >> 12;
      const int rem = r & 4095;
      const int mm = rem >> 9;
      const int ll = rem & 511;
      prow = (long long)((bb * cNB + (mm >> 2)) * cL + ll) * cD;
      tokoff = (long long)p.itok[bb * cL + ll] * cD;
    }
    float outv[8];
#pragma unroll
    for (int j = 0; j < 8; ++j) {
      const int c = col0 + tx * 8 + j;
      float v = acc[i][j];
      if (EPI == 1) {
        v = A[(long long)r * p.lda + c] + 0.1f * (v + bv[c]);
      } else if (EPI == 2) {
        const float gsum = v + p.aux1[prow + c] + bv[c];
        const float gate = 1.0f / (1.0f + expf(-gsum));
        v = A[(long long)r * p.lda + c] + gate * p.aux2[prow + c] +
            cSCALE * p.aux3[tokoff + c];
      }
      outv[j] = v;
    }
    float* cp = C + (long long)r * p.ldc + col0 + tx * 8;
    *(float4*)cp = *(float4*)&outv[0];
    *(float4*)(cp + 4) = *(float4*)&outv[4];
  }
}

// ---------------------------------------------------------------------------
// Split-bf16 MFMA NT GEMM, 3 planes per operand, 6 products (~fp32 precision,
// eps ~ 2^-26). C[r,c] = epi( sum_k A[r,k]*W[c,k] ).
// Tile 128x128, BK=32, 256 threads (4 waves 2x2), 4x4 16x16x32 frags/wave.
// CONVA=1: A is fp32, split in-kernel (down gemm). Otherwise pre-split planes.
// EPI: 0 plain | 3 v += recon(R planes)[r,c] (stride 512) | 4 v = silu(aux)*v
// ---------------------------------------------------------------------------
struct SGemmP {
  const short* A0; const short* A1; const short* A2;  // A planes [rows][lda]
  const float* Afp;                                   // CONVA=1 fp32 A
  int lda;
  const short* W0; const short* W1; const short* W2;  // W planes [N][Kd]
  float* C; int ldc;
  int Kd;
  const short* R0; const short* R1; const short* R2;  // EPI3 resid planes
  const float* aux;                                   // EPI4 g buffer
};

template <int EPI, int CONVA>
__global__ __launch_bounds__(256) void sgemm_k(SGemmP p) {
  __shared__ __align__(16) short As0[4096];
  __shared__ __align__(16) short As1[4096];
  __shared__ __align__(16) short As2[4096];
  __shared__ __align__(16) short Bs0[4096];
  __shared__ __align__(16) short Bs1[4096];
  __shared__ __align__(16) short Bs2[4096];
  const int tid = threadIdx.x;
  const int lane = tid & 63;
  const int wv = tid >> 6;
  const int wr = wv >> 1, wc = wv & 1;
  const int row0 = blockIdx.y * 128, col0 = blockIdx.x * 128;
  const int fr = lane & 15;
  const int kq = lane >> 4;

  const f32x4 fz = {0.f, 0.f, 0.f, 0.f};
  f32x4 acc[4][4];
#pragma unroll
  for (int i = 0; i < 4; ++i)
#pragma unroll
    for (int j = 0; j < 4; ++j) acc[i][j] = fz;

  const int sr = tid >> 2;         // 0..63
  const int so = (tid & 3) * 8;    // 0,8,16,24 (shorts)
  const int ldsoff = sr * 32 + so; // lane-linear *16B within wave
  const int cr = tid >> 1;         // CONVA row 0..127
  const int cc = (tid & 1) * 16;   // CONVA col offset (shorts)

  for (int k0 = 0; k0 < p.Kd; k0 += 32) {
    {
      const long long wb = (long long)(col0 + sr) * p.Kd + k0 + so;
      const long long wb2 = wb + 64LL * p.Kd;
      gload16(p.W0 + wb, &Bs0[ldsoff]);
      gload16(p.W0 + wb2, &Bs0[ldsoff + 2048]);
      gload16(p.W1 + wb, &Bs1[ldsoff]);
      gload16(p.W1 + wb2, &Bs1[ldsoff + 2048]);
      gload16(p.W2 + wb, &Bs2[ldsoff]);
      gload16(p.W2 + wb2, &Bs2[ldsoff + 2048]);
    }
    if (!CONVA) {
      const long long ab = (long long)(row0 + sr) * p.lda + k0 + so;
      const long long ab2 = ab + 64LL * p.lda;
      gload16(p.A0 + ab, &As0[ldsoff]);
      gload16(p.A0 + ab2, &As0[ldsoff + 2048]);
      gload16(p.A1 + ab, &As1[ldsoff]);
      gload16(p.A1 + ab2, &As1[ldsoff + 2048]);
      gload16(p.A2 + ab, &As2[ldsoff]);
      gload16(p.A2 + ab2, &As2[ldsoff + 2048]);
    } else {
      const float* ap = p.Afp + (long long)(row0 + cr) * p.lda + k0 + cc;
      float xv[16];
      *(float4*)&xv[0] = *(const float4*)(ap + 0);
      *(float4*)&xv[4] = *(const float4*)(ap + 4);
      *(float4*)&xv[8] = *(const float4*)(ap + 8);
      *(float4*)&xv[12] = *(const float4*)(ap + 12);
      short h[16], m[16], l2[16];
#pragma unroll
      for (int j = 0; j < 16; ++j) split3w(xv[j], h[j], m[j], l2[j]);
      const int wo = cr * 32 + cc;
      *(bf16x8*)&As0[wo] = *(bf16x8*)&h[0];
      *(bf16x8*)&As0[wo + 8] = *(bf16x8*)&h[8];
      *(bf16x8*)&As1[wo] = *(bf16x8*)&m[0];
      *(bf16x8*)&As1[wo + 8] = *(bf16x8*)&m[8];
      *(bf16x8*)&As2[wo] = *(bf16x8*)&l2[0];
      *(bf16x8*)&As2[wo + 8] = *(bf16x8*)&l2[8];
    }
    __syncthreads();

    bf16x8 a0[4], a1[4], a2[4];
#pragma unroll
    for (int mi = 0; mi < 4; ++mi) {
      const int ra = (wr * 64 + mi * 16 + fr) * 32 + kq * 8;
      a0[mi] = *(const bf16x8*)&As0[ra];
      a1[mi] = *(const bf16x8*)&As1[ra];
      a2[mi] = *(const bf16x8*)&As2[ra];
    }
#pragma unroll
    for (int ni = 0; ni < 4; ++ni) {
      const int rb = (wc * 64 + ni * 16 + fr) * 32 + kq * 8;
      bf16x8 b0 = *(const bf16x8*)&Bs0[rb];
      bf16x8 b1 = *(const bf16x8*)&Bs1[rb];
      bf16x8 b2 = *(const bf16x8*)&Bs2[rb];
#pragma unroll
      for (int mi = 0; mi < 4; ++mi) {
        f32x4 t = acc[mi][ni];
        // small terms first for accumulation accuracy
        t = __builtin_amdgcn_mfma_f32_16x16x32_bf16(a1[mi], b1, t, 0, 0, 0);
        t = __builtin_amdgcn_mfma_f32_16x16x32_bf16(a2[mi], b0, t, 0, 0, 0);
        t = __builtin_amdgcn_mfma_f32_16x16x32_bf16(a0[mi], b2, t, 0, 0, 0);
        t = __builtin_amdgcn_mfma_f32_16x16x32_bf16(a1[mi], b0, t, 0, 0, 0);
        t = __builtin_amdgcn_mfma_f32_16x16x32_bf16(a0[mi], b1, t, 0, 0, 0);
        t = __builtin_amdgcn_mfma_f32_16x16x32_bf16(a0[mi], b0, t, 0, 0, 0);
        acc[mi][ni] = t;
      }
    }
    __syncthreads();
  }

  // D layout: col = lane&15, row = (lane>>4)*4 + q   [m89-verified]
#pragma unroll
  for (int mi = 0; mi < 4; ++mi) {
#pragma unroll
    for (int q = 0; q < 4; ++q) {
      const int row = row0 + wr * 64 + mi * 16 + kq * 4 + q;
#pragma unroll
      for (int ni = 0; ni < 4; ++ni) {
        const int col = col0 + wc * 64 + ni * 16 + fr;
        const long long off = (long long)row * p.ldc + col;
        float v = acc[mi][ni][q];
        if (EPI == 3) {
          const long long roff = (long long)row * 512 + col;
          v += b2f(p.R0[roff]) + b2f(p.R1[roff]) + b2f(p.R2[roff]);
        }
        if (EPI == 4) {
          const float g = p.aux[off];
          v = (g / (1.0f + expf(-g))) * v;
        }
        p.C[off] = v;
      }
    }
  }
}

// ---------------------------------------------------------------------------
// fp32 -> 3 bf16 planes
// ---------------------------------------------------------------------------
__global__ __launch_bounds__(256) void split3_k(const float* __restrict__ in,
                                                short* __restrict__ o0,
                                                short* __restrict__ o1,
                                                short* __restrict__ o2, int n4) {
  const int i = blockIdx.x * 256 + threadIdx.x;
  if (i >= n4) return;
  float4 v = ((const float4*)in)[i];
  short a[4], b[4], c[4];
  split3w(v.x, a[0], b[0], c[0]);
  split3w(v.y, a[1], b[1], c[1]);
  split3w(v.z, a[2], b[2], c[2]);
  split3w(v.w, a[3], b[3], c[3]);
  *(short4*)&o0[(long long)i * 4] = make_short4(a[0], a[1], a[2], a[3]);
  *(short4*)&o1[(long long)i * 4] = make_short4(b[0], b[1], b[2], b[3]);
  *(short4*)&o2[(long long)i * 4] = make_short4(c[0], c[1], c[2], c[3]);
}

// ---------------------------------------------------------------------------
// RoPE table (match numpy float64 build, cast f32)
// ---------------------------------------------------------------------------
__global__ void ropetab_k(float* cosT, float* sinT) {
  const int i = blockIdx.x * 256 + threadIdx.x;
  if (i >= cL * 32) return;
  const int l = i >> 5;
  const int j = i & 31;
  const double inv = pow(10000.0, -(double)j / 32.0);
  const double a = (double)l * inv;
  const float c = (float)cos(a);
  const float s = (float)sin(a);
  cosT[l * 64 + j] = c; cosT[l * 64 + j + 32] = c;
  sinT[l * 64 + j] = s; sinT[l * 64 + j + 32] = s;
}

// ---------------------------------------------------------------------------
// RoPE apply in-place on q,k halves of qkv buffer (rows x 1536)
// ---------------------------------------------------------------------------
__global__ void rope_k(float* qkv, const float* __restrict__ cosT,
                       const float* __restrict__ sinT) {
  const long long idx = (long long)blockIdx.x * 256 + threadIdx.x;
  const int row = (int)(idx >> 9);
  const int pid = (int)(idx & 511);
  const int part = pid >> 8;
  const int rem = pid & 255;
  const int hh = rem >> 5;
  const int d = rem & 31;
  const int l = row & 511;
  float* base = qkv + (long long)row * 1536 + part * 512 + hh * 64 + d;
  const float x1 = base[0];
  const float x2 = base[32];
  const float c = cosT[l * 64 + d];
  const float s = sinT[l * 64 + d];
  base[0] = x1 * c - x2 * s;
  base[32] = x2 * c + x1 * s;
}

// ---------------------------------------------------------------------------
// Flash attention. Output written as 3 bf16 planes (A of o-proj sgemm).
// ---------------------------------------------------------------------------
__global__ __launch_bounds__(256) void attn_k(const float* __restrict__ qkv,
                                              const float* __restrict__ bias,
                                              short* __restrict__ op0,
                                              short* __restrict__ op1,
                                              short* __restrict__ op2) {
  const int n = blockIdx.z;
  const int hh = blockIdx.y;
  const int q0 = blockIdx.x * 64;
  __shared__ float Qs[64][68];
  __shared__ float KVs[64][68];
  __shared__ float Ps[64][68];
  const int tid = threadIdx.x;
  const int tx = tid & 15;
  const int ty = tid >> 4;

#pragma unroll
  for (int i = 0; i < 4; ++i) {
    const int slot = tid + i * 256;
    const int r = slot >> 4;
    const int dq = (slot & 15) << 2;
    float4 v = *(const float4*)(qkv + (long long)(n * 512 + q0 + r) * 1536 + hh * 64 + dq);
    Qs[dq][r] = v.x; Qs[dq + 1][r] = v.y; Qs[dq + 2][r] = v.z; Qs[dq + 3][r] = v.w;
  }
  float m_i[4], l_i[4], oacc[4][4];
#pragma unroll
  for (int i = 0; i < 4; ++i) {
    m_i[i] = -INFINITY; l_i[i] = 0.0f;
#pragma unroll
    for (int j = 0; j < 4; ++j) oacc[i][j] = 0.0f;
  }
  __syncthreads();

  for (int k0 = 0; k0 < 512; k0 += 64) {
#pragma unroll
    for (int i = 0; i < 4; ++i) {
      const int slot = tid + i * 256;
      const int r = slot >> 4;
      const int dq = (slot & 15) << 2;
      float4 v = *(const float4*)(qkv + (long long)(n * 512 + k0 + r) * 1536 + 512 + hh * 64 + dq);
      KVs[dq][r] = v.x; KVs[dq + 1][r] = v.y; KVs[dq + 2][r] = v.z; KVs[dq + 3][r] = v.w;
    }
    __syncthreads();

    float s[4][4];
#pragma unroll
    for (int i = 0; i < 4; ++i)
#pragma unroll
      for (int j = 0; j < 4; ++j) s[i][j] = 0.0f;
    for (int d = 0; d < 64; ++d) {
      float a[4], b[4];
      *(float4*)a = *(const float4*)&Qs[d][ty * 4];
      *(float4*)b = *(const float4*)&KVs[d][tx * 4];
#pragma unroll
      for (int i = 0; i < 4; ++i)
#pragma unroll
        for (int j = 0; j < 4; ++j) s[i][j] = fmaf(a[i], b[j], s[i][j]);
    }
#pragma unroll
    for (int i = 0; i < 4; ++i) {
      float4 bb = *(const float4*)(bias + ((long long)hh * 512 + q0 + ty * 4 + i) * 512 + k0 + tx * 4);
      s[i][0] = fmaf(s[i][0], cISQ, bb.x);
      s[i][1] = fmaf(s[i][1], cISQ, bb.y);
      s[i][2] = fmaf(s[i][2], cISQ, bb.z);
      s[i][3] = fmaf(s[i][3], cISQ, bb.w);
    }
#pragma unroll
    for (int i = 0; i < 4; ++i) {
      float rmax = fmaxf(fmaxf(s[i][0], s[i][1]), fmaxf(s[i][2], s[i][3]));
      for (int off = 1; off < 16; off <<= 1) rmax = fmaxf(rmax, __shfl_xor(rmax, off));
      const float mnew = fmaxf(m_i[i], rmax);
      const float sc = expf(m_i[i] - mnew);
      const float p0 = expf(s[i][0] - mnew);
      const float p1 = expf(s[i][1] - mnew);
      const float p2 = expf(s[i][2] - mnew);
      const float p3 = expf(s[i][3] - mnew);
      float rs = p0 + p1 + p2 + p3;
      for (int off = 1; off < 16; off <<= 1) rs += __shfl_xor(rs, off);
      l_i[i] = l_i[i] * sc + rs;
      m_i[i] = mnew;
#pragma unroll
      for (int j = 0; j < 4; ++j) oacc[i][j] *= sc;
      float4 pv = make_float4(p0, p1, p2, p3);
      *(float4*)&Ps[ty * 4 + i][tx * 4] = pv;
    }
    __syncthreads();

#pragma unroll
    for (int i = 0; i < 4; ++i) {
      const int slot = tid + i * 256;
      const int r = slot >> 4;
      const int dq = (slot & 15) << 2;
      float4 v = *(const float4*)(qkv + (long long)(n * 512 + k0 + r) * 1536 + 1024 + hh * 64 + dq);
      *(float4*)&KVs[r][dq] = v;
    }
    __syncthreads();

    for (int k = 0; k < 64; k += 4) {
      float pvals[4][4], vvals[4][4];
#pragma unroll
      for (int t = 0; t < 4; ++t) *(float4*)&vvals[t][0] = *(const float4*)&KVs[k + t][tx * 4];
#pragma unroll
      for (int i = 0; i < 4; ++i) *(float4*)&pvals[i][0] = *(const float4*)&Ps[ty * 4 + i][k];
#pragma unroll
      for (int i = 0; i < 4; ++i)
#pragma unroll
        for (int j = 0; j < 4; ++j)
#pragma unroll
          for (int t = 0; t < 4; ++t) oacc[i][j] = fmaf(pvals[i][t], vvals[t][j], oacc[i][j]);
    }
    __syncthreads();
  }

#pragma unroll
  for (int i = 0; i < 4; ++i) {
    const float inv = 1.0f / l_i[i];
    float ox[4] = {oacc[i][0] * inv, oacc[i][1] * inv, oacc[i][2] * inv, oacc[i][3] * inv};
    short u0[4], u1[4], u2[4];
#pragma unroll
    for (int j = 0; j < 4; ++j) split3w(ox[j], u0[j], u1[j], u2[j]);
    const long long ob = (long long)(n * 512 + q0 + ty * 4 + i) * 512 + hh * 64 + tx * 4;
    *(short4*)&op0[ob] = make_short4(u0[0], u0[1], u0[2], u0[3]);
    *(short4*)&op1[ob] = make_short4(u1[0], u1[1], u1[2], u1[3]);
    *(short4*)&op2[ob] = make_short4(u2[0], u2[1], u2[2], u2[3]);
  }
}

// ---------------------------------------------------------------------------
// Row RMS norm: fp32 in -> 3 bf16 planes out
// ---------------------------------------------------------------------------
__global__ __launch_bounds__(128) void rms3_k(const float* __restrict__ in,
                                              short* __restrict__ o0,
                                              short* __restrict__ o1,
                                              short* __restrict__ o2) {
  const int row = blockIdx.x;
  const int t = threadIdx.x;
  float4 v = *(const float4*)(in + (long long)row * 512 + t * 4);
  float ss = v.x * v.x + v.y * v.y + v.z * v.z + v.w * v.w;
  for (int off = 1; off < 64; off <<= 1) ss += __shfl_xor(ss, off);
  __shared__ float sred[2];
  if ((t & 63) == 0) sred[t >> 6] = ss;
  __syncthreads();
  const float tot = sred[0] + sred[1];
  const float sc = 1.0f / sqrtf(tot * (1.0f / 512.0f) + 1e-5f);
  float ov[4] = {v.x * sc, v.y * sc, v.z * sc, v.w * sc};
  short a[4], b[4], c[4];
#pragma unroll
  for (int j = 0; j < 4; ++j) split3w(ov[j], a[j], b[j], c[j]);
  const long long pb = (long long)row * 512 + t * 4;
  *(short4*)&o0[pb] = make_short4(a[0], a[1], a[2], a[3]);
  *(short4*)&o1[pb] = make_short4(b[0], b[1], b[2], b[3]);
  *(short4*)&o2[pb] = make_short4(c[0], c[1], c[2], c[3]);
}

// ---------------------------------------------------------------------------
// Value head (reads h planes)
// ---------------------------------------------------------------------------
__global__ __launch_bounds__(256) void vals_k(const short* __restrict__ hp0,
                                              const short* __restrict__ hp1,
                                              const short* __restrict__ hp2,
                                              const float* __restrict__ vW1,
                                              const float* __restrict__ vb1,
                                              const float* __restrict__ vW2,
                                              const float* __restrict__ vb2,
                                              float* out_vals, float* ws_vals) {
  const int bm = blockIdx.x;  // 0..31
  const int t = threadIdx.x;
  __shared__ float prow[512];
  __shared__ float wsum[4];
  const long long pb = (long long)bm * 262144;  // row l=0 of this (b,m)
  prow[t * 2] = rec3(hp0, hp1, hp2, pb + t * 2);
  prow[t * 2 + 1] = rec3(hp0, hp1, hp2, pb + t * 2 + 1);
  __syncthreads();
  float acc = 0.0f;
  const float* wrow = vW1 + (long long)t * 512;
  for (int d = 0; d < 512; d += 4) {
    float4 wv = *(const float4*)&wrow[d];
    float4 pv = *(const float4*)&prow[d];
    acc = fmaf(wv.x, pv.x, acc); acc = fmaf(wv.y, pv.y, acc);
    acc = fmaf(wv.z, pv.z, acc); acc = fmaf(wv.w, pv.w, acc);
  }
  acc += vb1[t];
  const float g = 0.5f * acc * (1.0f + erff(acc * 0.7071067811865475f));
  float part = g * vW2[t];
  for (int off = 1; off < 64; off <<= 1) part += __shfl_xor(part, off);
  if ((t & 63) == 0) wsum[t >> 6] = part;
  __syncthreads();
  if (t == 0) {
    const float v = wsum[0] + wsum[1] + wsum[2] + wsum[3] + vb2[0];
    out_vals[bm] = v;
    ws_vals[bm] = v;
  }
}

// ---------------------------------------------------------------------------
// Beam selection (tiny; reads h planes)
// ---------------------------------------------------------------------------
__global__ void select_k(const float* __restrict__ ws_vals, const float* __restrict__ beam,
                         const short* __restrict__ hp0, const short* __restrict__ hp1,
                         const short* __restrict__ hp2, const float* __restrict__ qW,
                         const float* __restrict__ qb, float* out_topv, float* out_qlog,
                         int* iTopI, int* iBest) {
  const int t = threadIdx.x;
  if (t < cB) {
    const int b = t;
    float sc[8];
    for (int m = 0; m < 8; ++m)
      sc[m] = 0.5f * ws_vals[b * 8 + m] + 0.5f * beam[b * 2 + (m >> 2)];
    int i1 = 0;
    for (int m = 1; m < 8; ++m) if (sc[m] > sc[i1]) i1 = m;
    int i2 = -1;
    for (int m = 0; m < 8; ++m) {
      if (m == i1) continue;
      if (i2 < 0 || sc[m] > sc[i2]) i2 = m;
    }
    out_topv[b * 2] = sc[i1];
    out_topv[b * 2 + 1] = sc[i2];
    iTopI[b * 2] = i1; iTopI[b * 2 + 1] = i2;
    iBest[b] = i1;
    const long long pb = (long long)(b * 8 + i1) * 262144;
    for (int j = 0; j < 2; ++j) {
      float acc = qb[j];
      for (int d = 0; d < 512; ++d)
        acc = fmaf(rec3(hp0, hp1, hp2, pb + d), qW[j * 512 + d], acc);
      out_qlog[b * 2 + j] = acc;
    }
  }
}

// new_z gather from h planes (reconstruct fp32)
__global__ void newz_k(const short* __restrict__ hp0, const short* __restrict__ hp1,
                       const short* __restrict__ hp2, const int* __restrict__ iTopI,
                       float* __restrict__ out) {
  const int f = blockIdx.x * 256 + threadIdx.x;  // 0..524287 float4s
  const int e4 = f & 127;
  const int rowz = f >> 7;
  const int l = rowz & 511;
  const int bnb = rowz >> 9;
  const int b = bnb >> 1;
  const int mi = iTopI[bnb];
  const long long src = ((long long)(b * 8 + mi) * 512 + l) * 512 + e4 * 4;
  short4 s0 = *(const short4*)&hp0[src];
  short4 s1 = *(const short4*)&hp1[src];
  short4 s2 = *(const short4*)&hp2[src];
  float4 v = make_float4(b2f(s0.x) + b2f(s1.x) + b2f(s2.x),
                         b2f(s0.y) + b2f(s1.y) + b2f(s2.y),
                         b2f(s0.z) + b2f(s1.z) + b2f(s2.z),
                         b2f(s0.w) + b2f(s1.w) + b2f(s2.w));
  *(float4*)(out + (long long)f * 4) = v;
}

// h_best gather: plane-to-plane row copy (exact)
__global__ void hbest_k(const short* __restrict__ hp0, const short* __restrict__ hp1,
                        const short* __restrict__ hp2, const int* __restrict__ iBest,
                        short* __restrict__ hb0, short* __restrict__ hb1,
                        short* __restrict__ hb2) {
  const int idx = blockIdx.x * 256 + threadIdx.x;  // 0..262143 short4 units
  const int pl = blockIdx.y;
  const int row = idx >> 7;  // 0..2047
  const int e = idx & 127;
  const int b = row >> 9;
  const int l = row & 511;
  const long long src = ((long long)(b * 8 + iBest[b]) * 512 + l) * 512 + e * 4;
  const long long dst = (long long)row * 512 + e * 4;
  const short* sp = pl == 0 ? hp0 : (pl == 1 ? hp1 : hp2);
  short* dp = pl == 0 ? hb0 : (pl == 1 ? hb1 : hb2);
  *(short4*)&dp[dst] = *(const short4*)&sp[src];
}

// argmax over V per row (first occurrence on ties)
__global__ __launch_bounds__(256) void argmax_k(const float* __restrict__ logits,
                                                int* __restrict__ predTok) {
  const int row = blockIdx.x;
  const float* Lr = logits + (long long)row * cV;
  const int t = threadIdx.x;
  float bv = -INFINITY;
  int bi = 0x7fffffff;
  for (int v = t; v < cV; v += 256) {
    const float x = Lr[v];
    if (x > bv) { bv = x; bi = v; }
  }
  __shared__ float sv[256];
  __shared__ int si[256];
  sv[t] = bv; si[t] = bi;
  __syncthreads();
  for (int s = 128; s > 0; s >>= 1) {
    if (t < s) {
      if (sv[t + s] > sv[t] || (sv[t + s] == sv[t] && si[t + s] < si[t])) {
        sv[t] = sv[t + s]; si[t] = si[t + s];
      }
    }
    __syncthreads();
  }
  if (t == 0) predTok[row] = si[0];
}

__global__ void npred_k(const float* __restrict__ peW, const int* __restrict__ predTok,
                        float* __restrict__ out) {
  const int f = blockIdx.x * 256 + threadIdx.x;
  const int e4 = f & 127;
  const int rowz = f >> 7;
  const int l = rowz & 511;
  const int bnb = rowz >> 9;
  const int b = bnb >> 1;
  const int tok = predTok[b * 512 + l];
  float4 v = *(const float4*)(peW + (long long)tok * 512 + e4 * 4);
  v.x *= cSCALE; v.y *= cSCALE; v.z *= cSCALE; v.w *= cSCALE;
  *(float4*)(out + (long long)f * 4) = v;
}

GemmP base_p() {
  GemmP p;
  p.A = nullptr; p.lda = 0; p.sAz = 0; p.divA = 1;
  p.W = nullptr; p.ldw = 0; p.sWz = 0; p.modW = 1;
  p.C = nullptr; p.ldc = 0; p.sCz = 0;
  p.Kd = 0;
  p.aux1 = nullptr; p.aux2 = nullptr; p.aux3 = nullptr;
  p.bvec = nullptr; p.itok = nullptr;
  return p;
}

SGemmP base_sp() {
  SGemmP p;
  p.A0 = nullptr; p.A1 = nullptr; p.A2 = nullptr; p.Afp = nullptr; p.lda = 0;
  p.W0 = nullptr; p.W1 = nullptr; p.W2 = nullptr;
  p.C = nullptr; p.ldc = 0; p.Kd = 0;
  p.R0 = nullptr; p.R1 = nullptr; p.R2 = nullptr;
  p.aux = nullptr;
  return p;
}

}  // namespace

extern "C" void kernel_launch(void* const* d_in, const int* in_sizes, int n_in,
                              void* d_out, int out_size, void* d_ws, size_t ws_size,
                              hipStream_t stream) {
  const float* z_in     = (const float*)d_in[0];
  const float* pred_emb = (const float*)d_in[1];
  const float* beam     = (const float*)d_in[2];
  const int*   inputs   = (const int*)d_in[3];
  const float* embed_W  = (const float*)d_in[4];
  const float* pembed_W = (const float*)d_in[5];
  const float* branch_W = (const float*)d_in[6];
  const float* branch_b = (const float*)d_in[7];
  const float* fusion_W = (const float*)d_in[8];
  const float* fusion_b = (const float*)d_in[9];
  const float* qkv_w    = (const float*)d_in[10];
  const float* o_w      = (const float*)d_in[11];
  const float* gu_w     = (const float*)d_in[12];
  const float* down_w   = (const float*)d_in[13];
  const float* bias     = (const float*)d_in[14];
  const float* vW1      = (const float*)d_in[15];
  const float* vb1      = (const float*)d_in[16];
  const float* vW2      = (const float*)d_in[17];
  const float* vb2      = (const float*)d_in[18];
  const float* qW       = (const float*)d_in[19];
  const float* qb       = (const float*)d_in[20];
  const float* lm_W     = (const float*)d_in[21];
  float* out = (float*)d_out;

  // workspace layout (floats); total exactly 50,399,488 floats = 201.6 MB
  float* w = (float*)d_ws;
  float* cosT    = w;                  // 32768
  float* sinT    = w + 32768;          // 32768
  float* vals_ws = w + 65536;          // 32
  int*   iTopI   = (int*)(w + 65568);  // 8
  int*   iBest   = iTopI + 8;          // 4
  int*   iPred   = iBest + 4;          // 2048
  // region1: h planes (3 x [16384][512] bf16) = 12,582,912 floats
  short* hp0 = (short*)(w + 67840);
  short* hp1 = hp0 + 8388608;
  short* hp2 = hp1 + 8388608;
  // region2: w1 = 25,165,824 floats (qkv fp32 / g / t ; overlays below)
  float* w1 = w + 67840 + 12582912;
  // region3: 12,582,912 floats (o planes / weight planes / y2 / peproj / lm planes)
  float* r3 = w1 + 25165824;
  short* r3s = (short*)r3;

  // region3 overlays
  short* op0 = r3s;               // attn-out planes [16384][512] x3
  short* op1 = r3s + 8388608;
  short* op2 = r3s + 16777216;
  short* qw0 = r3s;               // qkv_w planes [1536][512] x3
  short* qw1 = r3s + 786432;
  short* qw2 = r3s + 1572864;
  short* gw0 = r3s;               // gu_w planes [3072][512] x3
  short* gw1 = r3s + 1572864;
  short* gw2 = r3s + 3145728;
  short* dw0 = r3s;               // down_w planes [512][1536] x3
  short* dw1 = r3s + 786432;
  short* dw2 = r3s + 1572864;
  short* lw0 = r3s;               // lm_W chunk planes [6400][512] x3
  short* lw1 = r3s + 3276800;
  short* lw2 = r3s + 6553600;
  float* peproj = r3;             // setup fp32 [4096][512]
  float* y2 = r3 + 1179648;       // down output fp32 [16384][512]

  // w1 overlays
  float* cand = w1;               // [16384][512]
  float* h0 = w1 + 8388608;       // fusion output fp32 [16384][512]
  short* ow0 = (short*)w1;        // o_w planes [512][512] x3
  short* ow1 = ow0 + 262144;
  short* ow2 = ow0 + 524288;
  float* ybuf = w1 + 393216;      // o-proj output fp32 [16384][512]
  short* hb0 = (short*)w1;        // h_best planes [2048][512] x3
  short* hb1 = hb0 + 1048576;
  short* hb2 = hb0 + 2097152;

  float* out_newz    = out;
  float* out_newpred = out + 2097152;
  float* out_topv    = out + 4194304;
  float* out_logits  = out + 4194312;
  float* out_qlog    = out + 69730312;
  float* out_vals    = out + 69730320;

  // 1. RoPE table
  ropetab_k<<<64, 256, 0, stream>>>(cosT, sinT);

  // 2. cand = zf + 0.1*(zf @ branch_W.T + branch_b)
  {
    GemmP p = base_p();
    p.A = z_in; p.lda = 512; p.sAz = 262144; p.divA = 4;
    p.W = branch_W; p.ldw = 512; p.sWz = 262144; p.modW = 4;
    p.C = cand; p.ldc = 512; p.sCz = 262144;
    p.Kd = 512; p.bvec = branch_b;
    gemm_k<1><<<dim3(4, 4, 32), 256, 0, stream>>>(p);
  }
  // 3. pe_proj = pred_embedding @ fusion_W[:,512:].T
  {
    GemmP p = base_p();
    p.A = pred_emb; p.lda = 512;
    p.W = fusion_W + 512; p.ldw = 1024;
    p.C = peproj; p.ldc = 512;
    p.Kd = 512;
    gemm_k<0><<<dim3(4, 32, 1), 256, 0, stream>>>(p);
  }
  // 4. fusion -> h0 fp32
  {
    GemmP p = base_p();
    p.A = cand; p.lda = 512;
    p.W = fusion_W; p.ldw = 1024;
    p.C = h0; p.ldc = 512;
    p.Kd = 512;
    p.aux1 = peproj; p.aux2 = pred_emb; p.aux3 = embed_W;
    p.bvec = fusion_b; p.itok = inputs;
    gemm_k<2><<<dim3(4, 128, 1), 256, 0, stream>>>(p);
  }
  // 5. h0 -> h planes
  split3_k<<<8192, 256, 0, stream>>>(h0, hp0, hp1, hp2, 2097152);

  // transformer layers
  for (int i = 0; i < 4; ++i) {
    // qkv_w -> planes (region3; prev y2/o planes dead)
    split3_k<<<768, 256, 0, stream>>>(qkv_w + (long long)i * 786432, qw0, qw1, qw2, 196608);
    // qkv = h @ qkv_w.T -> w1 fp32
    {
      SGemmP p = base_sp();
      p.A0 = hp0; p.A1 = hp1; p.A2 = hp2; p.lda = 512;
      p.W0 = qw0; p.W1 = qw1; p.W2 = qw2;
      p.C = w1; p.ldc = 1536; p.Kd = 512;
      sgemm_k<0, 0><<<dim3(12, 128), 256, 0, stream>>>(p);
    }
    rope_k<<<32768, 256, 0, stream>>>(w1, cosT, sinT);
    // attention -> o planes (region3; qkv_w planes dead)
    attn_k<<<dim3(8, 8, 32), 256, 0, stream>>>(w1, bias, op0, op1, op2);
    // o_w -> planes (head of w1; qkv fp32 dead after attn)
    split3_k<<<256, 256, 0, stream>>>(o_w + (long long)i * 262144, ow0, ow1, ow2, 65536);
    // y1 = o @ o_w.T + h  -> ybuf fp32
    {
      SGemmP p = base_sp();
      p.A0 = op0; p.A1 = op1; p.A2 = op2; p.lda = 512;
      p.W0 = ow0; p.W1 = ow1; p.W2 = ow2;
      p.C = ybuf; p.ldc = 512; p.Kd = 512;
      p.R0 = hp0; p.R1 = hp1; p.R2 = hp2;
      sgemm_k<3, 0><<<dim3(4, 128), 256, 0, stream>>>(p);
    }
    // h = rms(y1) -> planes
    rms3_k<<<16384, 128, 0, stream>>>(ybuf, hp0, hp1, hp2);
    // gu_w -> planes (region3; o planes dead)
    split3_k<<<1536, 256, 0, stream>>>(gu_w + (long long)i * 1572864, gw0, gw1, gw2, 393216);
    // g = h @ gu_w[:1536].T -> w1 (ow/ybuf dead)
    {
      SGemmP p = base_sp();
      p.A0 = hp0; p.A1 = hp1; p.A2 = hp2; p.lda = 512;
      p.W0 = gw0; p.W1 = gw1; p.W2 = gw2;
      p.C = w1; p.ldc = 1536; p.Kd = 512;
      sgemm_k<0, 0><<<dim3(12, 128), 256, 0, stream>>>(p);
    }
    // t = silu(g) * (h @ gu_w[1536:].T), in-place w1
    {
      SGemmP p = base_sp();
      p.A0 = hp0; p.A1 = hp1; p.A2 = hp2; p.lda = 512;
      p.W0 = gw0 + 786432; p.W1 = gw1 + 786432; p.W2 = gw2 + 786432;
      p.C = w1; p.ldc = 1536; p.Kd = 512;
      p.aux = w1;
      sgemm_k<4, 0><<<dim3(12, 128), 256, 0, stream>>>(p);
    }
    // down_w -> planes (region3 head; gu planes dead)
    split3_k<<<768, 256, 0, stream>>>(down_w + (long long)i * 786432, dw0, dw1, dw2, 196608);
    // y2 = t @ down_w.T + h  (A fp32 split in-kernel)
    {
      SGemmP p = base_sp();
      p.Afp = w1; p.lda = 1536;
      p.W0 = dw0; p.W1 = dw1; p.W2 = dw2;
      p.C = y2; p.ldc = 512; p.Kd = 1536;
      p.R0 = hp0; p.R1 = hp1; p.R2 = hp2;
      sgemm_k<3, 1><<<dim3(4, 128), 256, 0, stream>>>(p);
    }
    // h = rms(y2) -> planes
    rms3_k<<<16384, 128, 0, stream>>>(y2, hp0, hp1, hp2);
  }

  // value head + selection (from h planes)
  vals_k<<<32, 256, 0, stream>>>(hp0, hp1, hp2, vW1, vb1, vW2, vb2, out_vals, vals_ws);
  select_k<<<1, 64, 0, stream>>>(vals_ws, beam, hp0, hp1, hp2, qW, qb, out_topv,
                                 out_qlog, iTopI, iBest);
  newz_k<<<2048, 256, 0, stream>>>(hp0, hp1, hp2, iTopI, out_newz);
  hbest_k<<<dim3(1024, 3), 256, 0, stream>>>(hp0, hp1, hp2, iBest, hb0, hb1, hb2);

  // logits = h_best @ lm_W.T via split-MFMA, 5 chunks of 6400 vocab rows
  for (int c = 0; c < 5; ++c) {
    split3_k<<<3200, 256, 0, stream>>>(lm_W + (long long)c * 3276800, lw0, lw1, lw2, 819200);
    SGemmP p = base_sp();
    p.A0 = hb0; p.A1 = hb1; p.A2 = hb2; p.lda = 512;
    p.W0 = lw0; p.W1 = lw1; p.W2 = lw2;
    p.C = out_logits + (long long)c * 6400; p.ldc = 32000; p.Kd = 512;
    sgemm_k<0, 0><<<dim3(50, 16), 256, 0, stream>>>(p);
  }
  argmax_k<<<2048, 256, 0, stream>>>(out_logits, iPred);
  npred_k<<<2048, 256, 0, stream>>>(pembed_W, iPred, out_newpred);
}